// Round 1
// baseline (3014.064 us; speedup 1.0000x reference)
//
#include <hip/hip_runtime.h>
#include <hip/hip_bf16.h>
#include <math.h>

// Problem constants
#define BB 4
#define CC 256
#define NN 4096          // H*W
#define EE 96
#define NTOT (BB*NN)     // 16384 rows

// ---------------------------------------------------------------------------
// Kernel 1: channel LayerNorm + transpose to position-major.
// In:  x [B, C, N]   Out: Xt [B*N, C] (= x transposed), Xn [B*N, C] (normed)
// One block handles 64 positions of one batch; tile [256 c][64 p] in LDS.
// ---------------------------------------------------------------------------
__global__ void ln_kernel(const float* __restrict__ x,
                          const float* __restrict__ gamma,
                          const float* __restrict__ beta,
                          float* __restrict__ Xt, float* __restrict__ Xn) {
    __shared__ float tile[256 * 65];       // +1 pad breaks bank conflicts
    __shared__ float psum[4][64], psq[4][64];
    __shared__ float mu_s[64], rs_s[64];
    const int b  = blockIdx.x >> 6;        // 64 p-tiles per batch
    const int p0 = (blockIdx.x & 63) * 64;
    const int tid = threadIdx.x;
    const float* xb = x + (size_t)b * CC * NN;

    // load [256][64] tile, coalesced over p
    for (int i = 0; i < 64; ++i) {
        int idx = tid + i * 256;
        int c = idx >> 6, p = idx & 63;
        tile[c * 65 + p] = xb[(size_t)c * NN + p0 + p];
    }
    __syncthreads();

    // column (position) mean/var: 4 partial-sum threads per column
    {
        int col = tid & 63, part = tid >> 6;
        float s = 0.f, sq = 0.f;
        for (int r = part * 64; r < part * 64 + 64; ++r) {
            float v = tile[r * 65 + col];
            s += v; sq += v * v;
        }
        psum[part][col] = s; psq[part][col] = sq;
    }
    __syncthreads();
    if (tid < 64) {
        float S  = psum[0][tid] + psum[1][tid] + psum[2][tid] + psum[3][tid];
        float SQ = psq[0][tid] + psq[1][tid] + psq[2][tid] + psq[3][tid];
        float mu = S / 256.0f;
        float var = SQ / 256.0f - mu * mu;
        mu_s[tid] = mu;
        rs_s[tid] = rsqrtf(var + 1e-5f);
    }
    __syncthreads();

    // write transposed, coalesced over c (each thread owns one channel)
    float g = gamma[tid], bt = beta[tid];
    float* XtB = Xt + ((size_t)b * NN + p0) * CC;
    float* XnB = Xn + ((size_t)b * NN + p0) * CC;
    for (int p = 0; p < 64; ++p) {
        float v = tile[tid * 65 + p];
        XtB[p * CC + tid] = v;
        XnB[p * CC + tid] = (v - mu_s[p]) * rs_s[p] * g + bt;
    }
}

// ---------------------------------------------------------------------------
// Kernel 2 (templated): C[m,n] = sum_k A[m,k] * W[n,k]  (+ fused epilogues)
// MODE 0: plain store                    (K-proj, V, A2, Corrective)
// MODE 1: += mask[row]*w_qm[col], store  (Q-proj)
// MODE 2: A fused corr_in = [A2-Xt | Xn*mask], GELU store (Hidden)
// MODE 3: gate epilogue + transpose + residual writeback  (final)
// ---------------------------------------------------------------------------
#define TM 64
#define TN 64
#define TKG 32

__device__ __forceinline__ float gelu_exact(float v) {
    return 0.5f * v * (1.0f + erff(v * 0.70710678118654752f));
}

template <int MODE>
__global__ void gemm_k(const float* __restrict__ A,
                       const float* __restrict__ Wm,
                       float* __restrict__ Cout,
                       int Ktot, int Ncols, int lda, int ldw,
                       const float* __restrict__ mask,
                       const float* __restrict__ aux1,   // M1: w_qm; M2: Xt; M3: x
                       const float* __restrict__ aux2,   // M2: Xn;  M3: residual_scale
                       float* __restrict__ outp)         // M3: out
{
    __shared__ float smem[2 * TM * (TKG + 1)];           // 4224 floats
    float* As = smem;
    float* Ws = smem + TM * (TKG + 1);
    const int m0 = blockIdx.y * TM;
    const int n0 = blockIdx.x * TN;
    const int tid = threadIdx.x;
    float acc[4][4] = {};

    for (int k0 = 0; k0 < Ktot; k0 += TKG) {
        __syncthreads();
        #pragma unroll
        for (int i = 0; i < 8; ++i) {
            int idx = tid + i * 256;          // 0..2047
            int m = idx >> 5, k = idx & 31;
            int row = m0 + m, kk = k0 + k;
            float av;
            if (MODE == 2) {
                av = (kk < 256) ? (A[(size_t)row * 256 + kk] - aux1[(size_t)row * 256 + kk])
                                : (aux2[(size_t)row * 256 + (kk - 256)] * mask[row]);
            } else {
                av = A[(size_t)row * lda + kk];
            }
            As[m * (TKG + 1) + k] = av;
            float wv_ = (n0 + m < Ncols) ? Wm[(size_t)(n0 + m) * ldw + kk] : 0.0f;
            Ws[m * (TKG + 1) + k] = wv_;
        }
        __syncthreads();
        const int ty = tid >> 4, tx = tid & 15;
        #pragma unroll
        for (int kk = 0; kk < TKG; ++kk) {
            float a[4], bv[4];
            #pragma unroll
            for (int i = 0; i < 4; ++i) a[i]  = As[(ty * 4 + i) * (TKG + 1) + kk];
            #pragma unroll
            for (int j = 0; j < 4; ++j) bv[j] = Ws[(tx * 4 + j) * (TKG + 1) + kk];
            #pragma unroll
            for (int i = 0; i < 4; ++i)
                #pragma unroll
                for (int j = 0; j < 4; ++j) acc[i][j] += a[i] * bv[j];
        }
    }

    const int ty = tid >> 4, tx = tid & 15;
    if (MODE == 0 || MODE == 1 || MODE == 2) {
        #pragma unroll
        for (int i = 0; i < 4; ++i) {
            int row = m0 + ty * 4 + i;
            #pragma unroll
            for (int j = 0; j < 4; ++j) {
                int col = n0 + tx * 4 + j;
                if (col < Ncols) {
                    float v = acc[i][j];
                    if (MODE == 1) v += mask[row] * aux1[col];
                    if (MODE == 2) v = gelu_exact(v);
                    Cout[(size_t)row * Ncols + col] = v;
                }
            }
        }
    } else {  // MODE 3: gate + delta, transpose through LDS, out = x + delta
        float tanh_rs = tanhf(aux2[0]);
        __syncthreads();
        float* tileT = smem;                  // 64*65 = 4160 <= 4224
        #pragma unroll
        for (int i = 0; i < 4; ++i) {
            int row = m0 + ty * 4 + i;
            float mrow = mask[row];
            #pragma unroll
            for (int j = 0; j < 4; ++j) {
                int col = n0 + tx * 4 + j;
                float logit = acc[i][j] + mrow * Wm[(size_t)col * ldw + 256];
                float gate = (1.0f / (1.0f + __expf(-logit))) * mrow;
                float corr = A[(size_t)row * lda + col];
                tileT[(tx * 4 + j) * 65 + (ty * 4 + i)] = tanh_rs * gate * corr;
            }
        }
        __syncthreads();
        for (int idx = tid; idx < 64 * 64; idx += 256) {
            int cl = idx >> 6, pl = idx & 63;
            int grow = m0 + pl;
            int b = grow >> 12, p = grow & 4095;
            size_t o = ((size_t)b * CC + (n0 + cl)) * NN + p;
            outp[o] = aux1[o] + tileT[cl * 65 + pl];
        }
    }
}

// ---------------------------------------------------------------------------
// Kernel 3: row-wise L2 normalize Q and K (rows of length 96), 1 wave/row
// ---------------------------------------------------------------------------
__global__ void qknorm_kernel(float* __restrict__ Q, float* __restrict__ K) {
    const int tid = threadIdx.x;
    const int wrow = blockIdx.x * 4 + (tid >> 6);
    const int lane = tid & 63;
    float* base = (wrow < NTOT) ? (Q + (size_t)wrow * EE)
                                : (K + (size_t)(wrow - NTOT) * EE);
    float v0 = base[lane];
    float v1 = (lane < 32) ? base[64 + lane] : 0.0f;
    float ss = v0 * v0 + v1 * v1;
    #pragma unroll
    for (int off = 32; off; off >>= 1) ss += __shfl_xor(ss, off, 64);
    float sc = 1.0f / fmaxf(sqrtf(ss), 1e-12f);
    base[lane] = v0 * sc;
    if (lane < 32) base[64 + lane] = v1 * sc;
}

// ---------------------------------------------------------------------------
// Kernel 4: flash-style attention, fp32.
// Block = 256 thr, TQ=32 queries, loop over 32-key tiles (K,V staged in LDS).
// S phase: thread (q = tid>>3, 4 keys) -> online softmax state per 8-lane group.
// PV phase: wave w owns q in [w*8, w*8+8), lane owns 4 channels (float4).
// ---------------------------------------------------------------------------
#define TQ 32
#define TKK 32

__global__ __launch_bounds__(256) void attn_kernel(
    const float* __restrict__ Q, const float* __restrict__ K,
    const float* __restrict__ V, const float* __restrict__ mask,
    float* __restrict__ O)
{
    __shared__ float Qs[TQ * 100];     // rows padded 96->100 (bank + f4 align)
    __shared__ float Ks[TKK * 100];
    __shared__ float Vs[TKK * 256];
    __shared__ float Ps[TQ * 36];
    __shared__ float alpha_s[TQ];
    __shared__ float l_s[TQ];
    __shared__ float flg[TKK];

    const int b  = blockIdx.x >> 7;
    const int q0 = (blockIdx.x & 127) * TQ;
    const int tid = threadIdx.x;
    const size_t bN = (size_t)b * NN;
    const int qg = tid >> 3;      // S-phase row
    const int kg = tid & 7;
    const int wv = tid >> 6;      // wave id
    const int lane = tid & 63;
    const float scale = 1.02062072616f;   // 10/sqrt(96)

    for (int idx = tid; idx < TQ * 96; idx += 256) {
        int r = idx / 96, d = idx - r * 96;
        Qs[r * 100 + d] = Q[(bN + q0 + r) * 96 + d];
    }

    float m_run = -3.0e38f, l_run = 0.0f;
    float acc[8][4] = {};

    for (int k0 = 0; k0 < NN; k0 += TKK) {
        __syncthreads();   // prev PV done before restaging
        for (int idx = tid; idx < TKK * 96; idx += 256) {
            int r = idx / 96, d = idx - r * 96;
            Ks[r * 100 + d] = K[(bN + k0 + r) * 96 + d];
        }
        for (int idx = tid; idx < TKK * 256; idx += 256) {
            int r = idx >> 8, c = idx & 255;
            Vs[idx] = V[(bN + k0 + r) * 256 + c];
        }
        if (tid < TKK) flg[tid] = mask[bN + k0 + tid];
        __syncthreads();

        // ---- S phase ----
        float pv[4]; float smax = -3.0e38f;
        #pragma unroll
        for (int ki = 0; ki < 4; ++ki) {
            int key = kg + 8 * ki;
            float dot = 0.f;
            #pragma unroll
            for (int d4 = 0; d4 < 24; ++d4) {
                float4 qv = *(const float4*)&Qs[qg * 100 + d4 * 4];
                float4 kv = *(const float4*)&Ks[key * 100 + d4 * 4];
                dot += qv.x * kv.x + qv.y * kv.y + qv.z * kv.z + qv.w * kv.w;
            }
            float s = (flg[key] >= 0.5f) ? -10000.0f : dot * scale;
            pv[ki] = s;
            smax = fmaxf(smax, s);
        }
        smax = fmaxf(smax, __shfl_xor(smax, 1, 64));
        smax = fmaxf(smax, __shfl_xor(smax, 2, 64));
        smax = fmaxf(smax, __shfl_xor(smax, 4, 64));
        float m_new = fmaxf(m_run, smax);
        float lsum = 0.f;
        #pragma unroll
        for (int ki = 0; ki < 4; ++ki) {
            float p = __expf(pv[ki] - m_new);
            Ps[qg * 36 + kg + 8 * ki] = p;
            lsum += p;
        }
        lsum += __shfl_xor(lsum, 1, 64);
        lsum += __shfl_xor(lsum, 2, 64);
        lsum += __shfl_xor(lsum, 4, 64);
        float alpha = __expf(m_run - m_new);
        l_run = l_run * alpha + lsum;
        m_run = m_new;
        if (kg == 0) alpha_s[qg] = alpha;
        __syncthreads();

        // ---- PV phase ----
        #pragma unroll
        for (int qi = 0; qi < 8; ++qi) {
            float al = alpha_s[wv * 8 + qi];
            #pragma unroll
            for (int j = 0; j < 4; ++j) acc[qi][j] *= al;
        }
        #pragma unroll
        for (int kk = 0; kk < TKK; kk += 4) {
            float4 pq[8];
            #pragma unroll
            for (int qi = 0; qi < 8; ++qi)
                pq[qi] = *(const float4*)&Ps[(wv * 8 + qi) * 36 + kk];
            #pragma unroll
            for (int t = 0; t < 4; ++t) {
                float4 vvv = *(const float4*)&Vs[(kk + t) * 256 + lane * 4];
                #pragma unroll
                for (int qi = 0; qi < 8; ++qi) {
                    float p = (t == 0) ? pq[qi].x : (t == 1) ? pq[qi].y
                            : (t == 2) ? pq[qi].z : pq[qi].w;
                    acc[qi][0] += p * vvv.x;
                    acc[qi][1] += p * vvv.y;
                    acc[qi][2] += p * vvv.z;
                    acc[qi][3] += p * vvv.w;
                }
            }
        }
    }

    if (kg == 0) l_s[qg] = l_run;
    __syncthreads();
    #pragma unroll
    for (int qi = 0; qi < 8; ++qi) {
        int q = wv * 8 + qi;
        float inv = 1.0f / l_s[q];
        float4 o;
        o.x = acc[qi][0] * inv; o.y = acc[qi][1] * inv;
        o.z = acc[qi][2] * inv; o.w = acc[qi][3] * inv;
        *(float4*)&O[(bN + q0 + q) * 256 + lane * 4] = o;
    }
}

// ---------------------------------------------------------------------------
extern "C" void kernel_launch(void* const* d_in, const int* in_sizes, int n_in,
                              void* d_out, int out_size, void* d_ws, size_t ws_size,
                              hipStream_t stream) {
    const float* x     = (const float*)d_in[0];
    const float* mask  = (const float*)d_in[1];
    const float* gamma = (const float*)d_in[2];
    const float* beta  = (const float*)d_in[3];
    const float* wq    = (const float*)d_in[4];
    const float* wk    = (const float*)d_in[5];
    const float* wv    = (const float*)d_in[6];
    const float* w_out = (const float*)d_in[7];
    const float* w_qm  = (const float*)d_in[8];
    const float* wd1   = (const float*)d_in[9];
    const float* wd2   = (const float*)d_in[10];
    const float* wg    = (const float*)d_in[11];
    const float* rs    = (const float*)d_in[12];
    float* out = (float*)d_out;
    float* ws  = (float*)d_ws;

    const size_t NC = (size_t)NTOT * CC;   // 4,194,304
    const size_t NE = (size_t)NTOT * EE;   // 1,572,864
    float* Xt = ws;            // [B*N, C]
    float* Xn = Xt + NC;       // [B*N, C]
    float* Qb = Xn + NC;       // [B*N, E]
    float* Kb = Qb + NE;       // [B*N, E]
    float* Vb = Kb + NE;       // [B*N, C]  (later: Hidden)
    float* Ob = Vb + NC;       // [B*N, C]  (later: Corrective)
    float* A2 = Ob + NC;       // [B*N, C]
    // total: 5*NC + 2*NE floats = 96.5 MB of d_ws

    ln_kernel<<<256, 256, 0, stream>>>(x, gamma, beta, Xt, Xn);
    // Q = Xn @ wq^T + mask*w_qm ; K = Xn @ wk^T ; V = Xt @ wv^T
    gemm_k<1><<<dim3(2, 256), 256, 0, stream>>>(Xn, wq, Qb, 256, 96, 256, 256,
                                                mask, w_qm, nullptr, nullptr);
    gemm_k<0><<<dim3(2, 256), 256, 0, stream>>>(Xn, wk, Kb, 256, 96, 256, 256,
                                                mask, nullptr, nullptr, nullptr);
    gemm_k<0><<<dim3(4, 256), 256, 0, stream>>>(Xt, wv, Vb, 256, 256, 256, 256,
                                                mask, nullptr, nullptr, nullptr);
    qknorm_kernel<<<8192, 256, 0, stream>>>(Qb, Kb);
    attn_kernel<<<512, 256, 0, stream>>>(Qb, Kb, Vb, mask, Ob);
    // A2 = O @ w_out^T
    gemm_k<0><<<dim3(4, 256), 256, 0, stream>>>(Ob, w_out, A2, 256, 256, 256, 256,
                                                mask, nullptr, nullptr, nullptr);
    // Hidden = gelu([A2-Xt | Xn*mask] @ wd1^T)   (into Vb, V is dead)
    gemm_k<2><<<dim3(4, 256), 256, 0, stream>>>(A2, wd1, Vb, 512, 256, 256, 512,
                                                mask, Xt, Xn, nullptr);
    // Corrective = Hidden @ wd2^T                (into Ob, O is dead)
    gemm_k<0><<<dim3(4, 256), 256, 0, stream>>>(Vb, wd2, Ob, 256, 256, 256, 256,
                                                mask, nullptr, nullptr, nullptr);
    // out = x + tanh(rs)*gate*Corrective, gate = sigmoid(Corr@wg^T + mask*wg_last)*mask
    gemm_k<3><<<dim3(4, 256), 256, 0, stream>>>(Ob, wg, nullptr, 256, 256, 256, 257,
                                                mask, x, rs, out);
}

// Round 2
// 1146.495 us; speedup vs baseline: 2.6289x; 2.6289x over previous
//
#include <hip/hip_runtime.h>
#include <hip/hip_bf16.h>
#include <math.h>

// Problem constants
#define BB 4
#define CC 256
#define NN 4096          // H*W
#define EE 96
#define NTOT (BB*NN)     // 16384 rows

typedef __attribute__((ext_vector_type(8))) short bf16x8;
typedef __attribute__((ext_vector_type(4))) float f32x4;

__device__ __forceinline__ short f2bf(float x) {
    __hip_bfloat16 h = __float2bfloat16(x);
    return *reinterpret_cast<short*>(&h);
}

// ---------------------------------------------------------------------------
// Kernel 1: channel LayerNorm + transpose to position-major.
// ---------------------------------------------------------------------------
__global__ void ln_kernel(const float* __restrict__ x,
                          const float* __restrict__ gamma,
                          const float* __restrict__ beta,
                          float* __restrict__ Xt, float* __restrict__ Xn) {
    __shared__ float tile[256 * 65];
    __shared__ float psum[4][64], psq[4][64];
    __shared__ float mu_s[64], rs_s[64];
    const int b  = blockIdx.x >> 6;
    const int p0 = (blockIdx.x & 63) * 64;
    const int tid = threadIdx.x;
    const float* xb = x + (size_t)b * CC * NN;

    for (int i = 0; i < 64; ++i) {
        int idx = tid + i * 256;
        int c = idx >> 6, p = idx & 63;
        tile[c * 65 + p] = xb[(size_t)c * NN + p0 + p];
    }
    __syncthreads();
    {
        int col = tid & 63, part = tid >> 6;
        float s = 0.f, sq = 0.f;
        for (int r = part * 64; r < part * 64 + 64; ++r) {
            float v = tile[r * 65 + col];
            s += v; sq += v * v;
        }
        psum[part][col] = s; psq[part][col] = sq;
    }
    __syncthreads();
    if (tid < 64) {
        float S  = psum[0][tid] + psum[1][tid] + psum[2][tid] + psum[3][tid];
        float SQ = psq[0][tid] + psq[1][tid] + psq[2][tid] + psq[3][tid];
        float mu = S / 256.0f;
        float var = SQ / 256.0f - mu * mu;
        mu_s[tid] = mu;
        rs_s[tid] = rsqrtf(var + 1e-5f);
    }
    __syncthreads();
    float g = gamma[tid], bt = beta[tid];
    float* XtB = Xt + ((size_t)b * NN + p0) * CC;
    float* XnB = Xn + ((size_t)b * NN + p0) * CC;
    for (int p = 0; p < 64; ++p) {
        float v = tile[tid * 65 + p];
        XtB[p * CC + tid] = v;
        XnB[p * CC + tid] = (v - mu_s[p]) * rs_s[p] * g + bt;
    }
}

// ---------------------------------------------------------------------------
// Kernel 2 (templated fp32 GEMM): C[m,n] = sum_k A[m,k] * W[n,k] (+ epilogues)
// ---------------------------------------------------------------------------
#define TM 64
#define TN 64
#define TKG 32

__device__ __forceinline__ float gelu_exact(float v) {
    return 0.5f * v * (1.0f + erff(v * 0.70710678118654752f));
}

template <int MODE>
__global__ void gemm_k(const float* __restrict__ A,
                       const float* __restrict__ Wm,
                       float* __restrict__ Cout,
                       int Ktot, int Ncols, int lda, int ldw,
                       const float* __restrict__ mask,
                       const float* __restrict__ aux1,
                       const float* __restrict__ aux2,
                       float* __restrict__ outp)
{
    __shared__ float smem[2 * TM * (TKG + 1)];
    float* As = smem;
    float* Ws = smem + TM * (TKG + 1);
    const int m0 = blockIdx.y * TM;
    const int n0 = blockIdx.x * TN;
    const int tid = threadIdx.x;
    float acc[4][4] = {};

    for (int k0 = 0; k0 < Ktot; k0 += TKG) {
        __syncthreads();
        #pragma unroll
        for (int i = 0; i < 8; ++i) {
            int idx = tid + i * 256;
            int m = idx >> 5, k = idx & 31;
            int row = m0 + m, kk = k0 + k;
            float av;
            if (MODE == 2) {
                av = (kk < 256) ? (A[(size_t)row * 256 + kk] - aux1[(size_t)row * 256 + kk])
                                : (aux2[(size_t)row * 256 + (kk - 256)] * mask[row]);
            } else {
                av = A[(size_t)row * lda + kk];
            }
            As[m * (TKG + 1) + k] = av;
            float wv_ = (n0 + m < Ncols) ? Wm[(size_t)(n0 + m) * ldw + kk] : 0.0f;
            Ws[m * (TKG + 1) + k] = wv_;
        }
        __syncthreads();
        const int ty = tid >> 4, tx = tid & 15;
        #pragma unroll
        for (int kk = 0; kk < TKG; ++kk) {
            float a[4], bv[4];
            #pragma unroll
            for (int i = 0; i < 4; ++i) a[i]  = As[(ty * 4 + i) * (TKG + 1) + kk];
            #pragma unroll
            for (int j = 0; j < 4; ++j) bv[j] = Ws[(tx * 4 + j) * (TKG + 1) + kk];
            #pragma unroll
            for (int i = 0; i < 4; ++i)
                #pragma unroll
                for (int j = 0; j < 4; ++j) acc[i][j] += a[i] * bv[j];
        }
    }

    const int ty = tid >> 4, tx = tid & 15;
    if (MODE == 0 || MODE == 1 || MODE == 2) {
        #pragma unroll
        for (int i = 0; i < 4; ++i) {
            int row = m0 + ty * 4 + i;
            #pragma unroll
            for (int j = 0; j < 4; ++j) {
                int col = n0 + tx * 4 + j;
                if (col < Ncols) {
                    float v = acc[i][j];
                    if (MODE == 1) v += mask[row] * aux1[col];
                    if (MODE == 2) v = gelu_exact(v);
                    Cout[(size_t)row * Ncols + col] = v;
                }
            }
        }
    } else {  // MODE 3: gate + delta, transpose, residual writeback
        float tanh_rs = tanhf(aux2[0]);
        __syncthreads();
        float* tileT = smem;
        #pragma unroll
        for (int i = 0; i < 4; ++i) {
            int row = m0 + ty * 4 + i;
            float mrow = mask[row];
            #pragma unroll
            for (int j = 0; j < 4; ++j) {
                int col = n0 + tx * 4 + j;
                float logit = acc[i][j] + mrow * Wm[(size_t)col * ldw + 256];
                float gate = (1.0f / (1.0f + __expf(-logit))) * mrow;
                float corr = A[(size_t)row * lda + col];
                tileT[(tx * 4 + j) * 65 + (ty * 4 + i)] = tanh_rs * gate * corr;
            }
        }
        __syncthreads();
        for (int idx = tid; idx < 64 * 64; idx += 256) {
            int cl = idx >> 6, pl = idx & 63;
            int grow = m0 + pl;
            int b = grow >> 12, p = grow & 4095;
            size_t o = ((size_t)b * CC + (n0 + cl)) * NN + p;
            outp[o] = aux1[o] + tileT[cl * 65 + pl];
        }
    }
}

// ---------------------------------------------------------------------------
// Kernel 3: row-wise L2 normalize Q and K -> bf16 output buffers
// ---------------------------------------------------------------------------
__global__ void qknorm_kernel(const float* __restrict__ Q, const float* __restrict__ K,
                              short* __restrict__ Q16, short* __restrict__ K16) {
    const int tid = threadIdx.x;
    const int wrow = blockIdx.x * 4 + (tid >> 6);
    const int lane = tid & 63;
    const float* base = (wrow < NTOT) ? (Q + (size_t)wrow * EE)
                                      : (K + (size_t)(wrow - NTOT) * EE);
    short* obase = (wrow < NTOT) ? (Q16 + (size_t)wrow * EE)
                                 : (K16 + (size_t)(wrow - NTOT) * EE);
    float v0 = base[lane];
    float v1 = (lane < 32) ? base[64 + lane] : 0.0f;
    float ss = v0 * v0 + v1 * v1;
    #pragma unroll
    for (int off = 32; off; off >>= 1) ss += __shfl_xor(ss, off, 64);
    float sc = 1.0f / fmaxf(sqrtf(ss), 1e-12f);
    obase[lane] = f2bf(v0 * sc);
    if (lane < 32) obase[64 + lane] = f2bf(v1 * sc);
}

// ---------------------------------------------------------------------------
// Kernel 3b: transpose+convert V: Vb [B*N, C] fp32 -> V16t [B, C, N] bf16
// ---------------------------------------------------------------------------
__global__ void vtrans_kernel(const float* __restrict__ Vb, short* __restrict__ V16t) {
    __shared__ float tile[64][65];
    const int bid = blockIdx.x;
    const int b = bid >> 8;
    const int nt = (bid & 255) >> 2;
    const int ct = bid & 3;
    const int n0 = nt * 64, c0 = ct * 64;
    const int tid = threadIdx.x;
    #pragma unroll
    for (int i = 0; i < 16; ++i) {
        int idx = tid + i * 256;
        int nl = idx >> 6, cl = idx & 63;
        tile[cl][nl] = Vb[((size_t)b * NN + n0 + nl) * CC + c0 + cl];
    }
    __syncthreads();
    #pragma unroll
    for (int i = 0; i < 8; ++i) {
        int idx = tid + i * 256;
        int cl = idx >> 5, np = (idx & 31) * 2;
        unsigned int pk = (unsigned short)f2bf(tile[cl][np]) |
                          ((unsigned int)(unsigned short)f2bf(tile[cl][np + 1]) << 16);
        *(unsigned int*)&V16t[((size_t)b * CC + c0 + cl) * NN + n0 + np] = pk;
    }
}

// ---------------------------------------------------------------------------
// Kernel 4: MFMA flash attention (bf16, fixed-max softmax).
// 128 threads = 2 waves; wave w owns 16 queries; 32-key tiles.
// ---------------------------------------------------------------------------
#define KS_STRIDE 104   // bf16 elems per key row (96 + 8 pad, 16B aligned)
#define VS_STRIDE 56    // bf16 elems per channel row (32 + 24 pad, 16B aligned)
#define PS_STRIDE 40    // bf16 elems per P row (32 + 8 pad, 16B aligned)

__global__ __launch_bounds__(128) void attn_mfma_kernel(
    const short* __restrict__ Q16, const short* __restrict__ K16,
    const short* __restrict__ V16t, const float* __restrict__ mask,
    float* __restrict__ O)
{
    __shared__ short Ks[32 * KS_STRIDE];
    __shared__ short Vs[256 * VS_STRIDE];
    __shared__ short Ps[2][16 * PS_STRIDE];
    __shared__ float flg[32];

    const int tid = threadIdx.x;
    const int w = tid >> 6, lane = tid & 63;
    const int ln = lane & 15, quad = lane >> 4;
    const int b = blockIdx.x >> 7;
    const int q0 = (blockIdx.x & 127) * 32;
    const size_t bN = (size_t)b * NN;

    // Q fragments (A-operand layout), kept in registers for the whole loop
    bf16x8 qf[3];
    {
        const short* qrow = Q16 + (bN + q0 + w * 16 + ln) * EE;
        qf[0] = *(const bf16x8*)(qrow + quad * 8);
        qf[1] = *(const bf16x8*)(qrow + 32 + quad * 8);
        qf[2] = *(const bf16x8*)(qrow + 64 + quad * 8);
    }

    f32x4 acc[16];
    #pragma unroll
    for (int i = 0; i < 16; ++i) acc[i] = (f32x4){0.f, 0.f, 0.f, 0.f};
    float lsum[4] = {0.f, 0.f, 0.f, 0.f};

    const float C1 = 1.02062072615966f;   // 10/sqrt(96)

    for (int k0 = 0; k0 < NN; k0 += 32) {
        __syncthreads();   // everyone done reading Ks/Vs from prev iter
        // stage K tile: 32 keys x 96 bf16, contiguous in global
        {
            const short* kbase = K16 + (bN + k0) * EE;
            #pragma unroll
            for (int g = tid; g < 384; g += 128) {
                int key = g / 12, c16 = g % 12;
                *(bf16x8*)&Ks[key * KS_STRIDE + c16 * 8] = *(const bf16x8*)(kbase + g * 8);
            }
        }
        // stage V tile transposed: Vs[ch][key], 256 x 32 bf16
        {
            #pragma unroll
            for (int g = tid; g < 1024; g += 128) {
                int c = g >> 2, kc = g & 3;
                *(bf16x8*)&Vs[c * VS_STRIDE + kc * 8] =
                    *(const bf16x8*)&V16t[((size_t)b * CC + c) * NN + k0 + kc * 8];
            }
        }
        if (tid < 32) flg[tid] = mask[bN + k0 + tid];
        __syncthreads();

        // ---- S = Q K^T via MFMA (2 n-tiles of 16 keys, 3 k-steps of 32) ----
        f32x4 s0 = (f32x4){0.f, 0.f, 0.f, 0.f};
        f32x4 s1 = (f32x4){0.f, 0.f, 0.f, 0.f};
        #pragma unroll
        for (int e = 0; e < 3; ++e) {
            bf16x8 kf0 = *(const bf16x8*)&Ks[ln * KS_STRIDE + e * 32 + quad * 8];
            bf16x8 kf1 = *(const bf16x8*)&Ks[(16 + ln) * KS_STRIDE + e * 32 + quad * 8];
            s0 = __builtin_amdgcn_mfma_f32_16x16x32_bf16(qf[e], kf0, s0, 0, 0, 0);
            s1 = __builtin_amdgcn_mfma_f32_16x16x32_bf16(qf[e], kf1, s1, 0, 0, 0);
        }

        // ---- softmax numerator with fixed max (scores bounded by C1) ----
        bool m0 = flg[ln] >= 0.5f;
        bool m1 = flg[16 + ln] >= 0.5f;
        float p0[4], p1[4];
        #pragma unroll
        for (int r = 0; r < 4; ++r) {
            p0[r] = m0 ? 0.f : __expf(fmaf(s0[r], C1, -C1));
            p1[r] = m1 ? 0.f : __expf(fmaf(s1[r], C1, -C1));
            lsum[r] += p0[r] + p1[r];
        }

        // ---- P: C-layout -> LDS -> A-layout (per-wave buffer, no barrier) ----
        #pragma unroll
        for (int r = 0; r < 4; ++r) {
            Ps[w][(quad * 4 + r) * PS_STRIDE + ln]      = f2bf(p0[r]);
            Ps[w][(quad * 4 + r) * PS_STRIDE + 16 + ln] = f2bf(p1[r]);
        }
        bf16x8 pf = *(const bf16x8*)&Ps[w][ln * PS_STRIDE + quad * 8];

        // ---- O += P V  (16 n-tiles over C=256, one k-step of 32 keys) ----
        #pragma unroll
        for (int ct = 0; ct < 16; ++ct) {
            bf16x8 vf = *(const bf16x8*)&Vs[(ct * 16 + ln) * VS_STRIDE + quad * 8];
            acc[ct] = __builtin_amdgcn_mfma_f32_16x16x32_bf16(pf, vf, acc[ct], 0, 0, 0);
        }
    }

    // ---- epilogue: l reduction across the 16 key-lanes, normalize, store ----
    float linv[4];
    #pragma unroll
    for (int r = 0; r < 4; ++r) {
        float l = lsum[r];
        l += __shfl_xor(l, 1, 64);
        l += __shfl_xor(l, 2, 64);
        l += __shfl_xor(l, 4, 64);
        l += __shfl_xor(l, 8, 64);
        linv[r] = 1.0f / l;
    }
    #pragma unroll
    for (int ct = 0; ct < 16; ++ct) {
        #pragma unroll
        for (int r = 0; r < 4; ++r) {
            O[(bN + q0 + w * 16 + quad * 4 + r) * (size_t)CC + ct * 16 + ln] =
                acc[ct][r] * linv[r];
        }
    }
}

// ---------------------------------------------------------------------------
extern "C" void kernel_launch(void* const* d_in, const int* in_sizes, int n_in,
                              void* d_out, int out_size, void* d_ws, size_t ws_size,
                              hipStream_t stream) {
    const float* x     = (const float*)d_in[0];
    const float* mask  = (const float*)d_in[1];
    const float* gamma = (const float*)d_in[2];
    const float* beta  = (const float*)d_in[3];
    const float* wq    = (const float*)d_in[4];
    const float* wk    = (const float*)d_in[5];
    const float* wv    = (const float*)d_in[6];
    const float* w_out = (const float*)d_in[7];
    const float* w_qm  = (const float*)d_in[8];
    const float* wd1   = (const float*)d_in[9];
    const float* wd2   = (const float*)d_in[10];
    const float* wg    = (const float*)d_in[11];
    const float* rs    = (const float*)d_in[12];
    float* out = (float*)d_out;
    float* ws  = (float*)d_ws;

    const size_t NC = (size_t)NTOT * CC;   // 4,194,304
    const size_t NE = (size_t)NTOT * EE;   // 1,572,864
    float* Xt = ws;            // [B*N, C]
    float* Xn = Xt + NC;       // [B*N, C]
    float* Qb = Xn + NC;       // [B*N, E] fp32  (dead after qknorm)
    float* Kb = Qb + NE;       // [B*N, E] fp32  (dead after qknorm)
    float* Vb = Kb + NE;       // [B*N, C] fp32  (dead after vtrans)
    float* Ob = Vb + NC;       // [B*N, C] attn out / Corrective
    float* A2 = Ob + NC;       // [B*N, C]
    // bf16 aliases into dead fp32 regions:
    short* Q16  = (short*)Vb;          // NE bf16 (Vb dead: vtrans runs first)
    short* K16  = Q16 + NE;            // NE bf16
    short* V16t = (short*)A2;          // NC bf16 (A2 written only after attn)
    float* Hid  = Vb;                  // Hidden reuses Vb region after attn

    ln_kernel<<<256, 256, 0, stream>>>(x, gamma, beta, Xt, Xn);
    gemm_k<1><<<dim3(2, 256), 256, 0, stream>>>(Xn, wq, Qb, 256, 96, 256, 256,
                                                mask, w_qm, nullptr, nullptr);
    gemm_k<0><<<dim3(2, 256), 256, 0, stream>>>(Xn, wk, Kb, 256, 96, 256, 256,
                                                mask, nullptr, nullptr, nullptr);
    gemm_k<0><<<dim3(4, 256), 256, 0, stream>>>(Xt, wv, Vb, 256, 256, 256, 256,
                                                mask, nullptr, nullptr, nullptr);
    vtrans_kernel<<<1024, 256, 0, stream>>>(Vb, V16t);
    qknorm_kernel<<<8192, 256, 0, stream>>>(Qb, Kb, Q16, K16);
    attn_mfma_kernel<<<512, 128, 0, stream>>>(Q16, K16, V16t, mask, Ob);
    gemm_k<0><<<dim3(4, 256), 256, 0, stream>>>(Ob, w_out, A2, 256, 256, 256, 256,
                                                mask, nullptr, nullptr, nullptr);
    gemm_k<2><<<dim3(4, 256), 256, 0, stream>>>(A2, wd1, Hid, 512, 256, 256, 512,
                                                mask, Xt, Xn, nullptr);
    gemm_k<0><<<dim3(4, 256), 256, 0, stream>>>(Hid, wd2, Ob, 256, 256, 256, 256,
                                                mask, nullptr, nullptr, nullptr);
    gemm_k<3><<<dim3(4, 256), 256, 0, stream>>>(Ob, wg, nullptr, 256, 256, 256, 257,
                                                mask, x, rs, out);
}

// Round 3
// 368.222 us; speedup vs baseline: 8.1855x; 3.1136x over previous
//
#include <hip/hip_runtime.h>
#include <hip/hip_bf16.h>
#include <math.h>

// Problem constants
#define BB 4
#define CC 256
#define NN 4096          // H*W
#define EE 96
#define NTOT (BB*NN)     // 16384 rows

typedef __attribute__((ext_vector_type(8))) short bf16x8;
typedef __attribute__((ext_vector_type(4))) float f32x4;

__device__ __forceinline__ short f2bf(float x) {
    __hip_bfloat16 h = __float2bfloat16(x);
    return *reinterpret_cast<short*>(&h);
}
__device__ __forceinline__ float bf2f(short s) {
    unsigned int u = ((unsigned int)(unsigned short)s) << 16;
    float f;
    __builtin_memcpy(&f, &u, 4);
    return f;
}
__device__ __forceinline__ float gelu_exact(float v) {
    return 0.5f * v * (1.0f + erff(v * 0.70710678118654752f));
}

// Weight arena offsets (shorts)
#define OFF_WQ  0
#define OFF_WK  24576
#define OFF_WV  49152
#define OFF_WO  114688
#define OFF_WD1 180224
#define OFF_WD2 311296
#define OFF_WG  376832
#define W16_TOTAL 442624

// ---------------------------------------------------------------------------
// Weight fp32 -> bf16 converter (one pass over all weights)
// ---------------------------------------------------------------------------
__global__ void wconv_kernel(const float* __restrict__ wq, const float* __restrict__ wk,
                             const float* __restrict__ wv, const float* __restrict__ wo,
                             const float* __restrict__ wd1, const float* __restrict__ wd2,
                             const float* __restrict__ wg, short* __restrict__ W16) {
    int i = blockIdx.x * 256 + threadIdx.x;
    if (i >= W16_TOTAL) return;
    const float* src; int off;
    if      (i < OFF_WK)  { src = wq;  off = OFF_WQ;  }
    else if (i < OFF_WV)  { src = wk;  off = OFF_WK;  }
    else if (i < OFF_WO)  { src = wv;  off = OFF_WV;  }
    else if (i < OFF_WD1) { src = wo;  off = OFF_WO;  }
    else if (i < OFF_WD2) { src = wd1; off = OFF_WD1; }
    else if (i < OFF_WG)  { src = wd2; off = OFF_WD2; }
    else                  { src = wg;  off = OFF_WG;  }
    W16[i] = f2bf(src[i - off]);
}

// ---------------------------------------------------------------------------
// Kernel 1: channel LayerNorm + transpose; emits bf16 Xt16, Xn16, Xnm16 (=Xn*mask)
// ---------------------------------------------------------------------------
__global__ void ln_kernel(const float* __restrict__ x,
                          const float* __restrict__ gamma,
                          const float* __restrict__ beta,
                          const float* __restrict__ mask,
                          short* __restrict__ Xt16, short* __restrict__ Xn16,
                          short* __restrict__ Xnm16) {
    __shared__ float tile[256 * 65];
    __shared__ float psum[4][64], psq[4][64];
    __shared__ float mu_s[64], rs_s[64], mk_s[64];
    const int b  = blockIdx.x >> 6;
    const int p0 = (blockIdx.x & 63) * 64;
    const int tid = threadIdx.x;
    const float* xb = x + (size_t)b * CC * NN;

    for (int i = 0; i < 64; ++i) {
        int idx = tid + i * 256;
        int c = idx >> 6, p = idx & 63;
        tile[c * 65 + p] = xb[(size_t)c * NN + p0 + p];
    }
    if (tid < 64) mk_s[tid] = mask[(size_t)b * NN + p0 + tid];
    __syncthreads();
    {
        int col = tid & 63, part = tid >> 6;
        float s = 0.f, sq = 0.f;
        for (int r = part * 64; r < part * 64 + 64; ++r) {
            float v = tile[r * 65 + col];
            s += v; sq += v * v;
        }
        psum[part][col] = s; psq[part][col] = sq;
    }
    __syncthreads();
    if (tid < 64) {
        float S  = psum[0][tid] + psum[1][tid] + psum[2][tid] + psum[3][tid];
        float SQ = psq[0][tid] + psq[1][tid] + psq[2][tid] + psq[3][tid];
        float mu = S / 256.0f;
        float var = SQ / 256.0f - mu * mu;
        mu_s[tid] = mu;
        rs_s[tid] = rsqrtf(var + 1e-5f);
    }
    __syncthreads();
    float g = gamma[tid], bt = beta[tid];
    size_t rowbase = ((size_t)b * NN + p0) * CC;
    for (int p = 0; p < 64; ++p) {
        float v = tile[tid * 65 + p];
        float xn = (v - mu_s[p]) * rs_s[p] * g + bt;
        Xt16[rowbase + p * CC + tid]  = f2bf(v);
        Xn16[rowbase + p * CC + tid]  = f2bf(xn);
        Xnm16[rowbase + p * CC + tid] = f2bf(xn * mk_s[p]);
    }
}

// ---------------------------------------------------------------------------
// Kernel 2: bf16 MFMA GEMM, C[m,n] = sum_k A[m,k]*W[n,k], fused epilogues.
// Block: 256 thr / 4 waves; tile 64 m x NT*16 n; wave w owns rows [16w,16w+16).
// MODE 0: Q-proj (+mask*w_qm, fp32 out, N=96)
// MODE 1: K-proj (fp32 out, N=96)
// MODE 2: V-proj -> transposed bf16 store to V16t [B,C,N]
// MODE 3: w_out  -> store bf16 (acc - Xt16)          (D1in)
// MODE 4: wd1, split-A [D1in | Xnm], K=512, GELU -> bf16 (Hidden)
// MODE 5: plain bf16 store                            (Corrective)
// MODE 6: gate epilogue + residual + transpose to out [B,C,N] fp32
// ---------------------------------------------------------------------------
template <int NT, int KT, int MODE>
__global__ __launch_bounds__(256) void mgemm(
    const short* __restrict__ A16, const short* __restrict__ A16b,
    const short* __restrict__ W16, int ldw,
    const float* __restrict__ mask, const float* __restrict__ auxf,
    const short* __restrict__ auxb,
    float* __restrict__ outf, short* __restrict__ outb,
    const float* __restrict__ xres)
{
    constexpr int K = KT * 32;
    __shared__ short As[64 * 40];
    __shared__ short Ws[NT * 16 * 40];
    const int tid = threadIdx.x;
    const int w = tid >> 6, lane = tid & 63, ln = lane & 15, quad = lane >> 4;
    const int m0 = blockIdx.x * 64;

    f32x4 acc[NT];
    #pragma unroll
    for (int i = 0; i < NT; ++i) acc[i] = (f32x4){0.f, 0.f, 0.f, 0.f};

    for (int kt = 0; kt < KT; ++kt) {
        const int k0 = kt * 32;
        __syncthreads();
        {
            int m = tid >> 2, kc = tid & 3;
            int kk = k0 + kc * 8;
            const short* src;
            if (MODE == 4) {
                src = (kk < 256) ? &A16[(size_t)(m0 + m) * 256 + kk]
                                 : &A16b[(size_t)(m0 + m) * 256 + kk - 256];
            } else {
                src = &A16[(size_t)(m0 + m) * K + kk];
            }
            *(bf16x8*)&As[m * 40 + kc * 8] = *(const bf16x8*)src;
        }
        for (int i = tid; i < NT * 64; i += 256) {
            int n = i >> 2, kc = i & 3;
            *(bf16x8*)&Ws[n * 40 + kc * 8] =
                *(const bf16x8*)&W16[(size_t)n * ldw + k0 + kc * 8];
        }
        __syncthreads();
        bf16x8 af = *(const bf16x8*)&As[(w * 16 + ln) * 40 + quad * 8];
        #pragma unroll
        for (int nt = 0; nt < NT; ++nt) {
            bf16x8 bf = *(const bf16x8*)&Ws[(nt * 16 + ln) * 40 + quad * 8];
            acc[nt] = __builtin_amdgcn_mfma_f32_16x16x32_bf16(af, bf, acc[nt], 0, 0, 0);
        }
    }

    const int rowb = m0 + w * 16 + quad * 4;
    if (MODE == 0 || MODE == 1) {
        #pragma unroll
        for (int nt = 0; nt < NT; ++nt) {
            int col = nt * 16 + ln;
            #pragma unroll
            for (int r = 0; r < 4; ++r) {
                float v = acc[nt][r];
                if (MODE == 0) v += mask[rowb + r] * auxf[col];
                outf[(size_t)(rowb + r) * EE + col] = v;
            }
        }
    } else if (MODE == 3 || MODE == 4 || MODE == 5) {
        #pragma unroll
        for (int nt = 0; nt < NT; ++nt) {
            int col = nt * 16 + ln;
            #pragma unroll
            for (int r = 0; r < 4; ++r) {
                float v = acc[nt][r];
                if (MODE == 3) v -= bf2f(auxb[(size_t)(rowb + r) * 256 + col]);
                if (MODE == 4) v = gelu_exact(v);
                outb[(size_t)(rowb + r) * 256 + col] = f2bf(v);
            }
        }
    } else if (MODE == 2) {
        short* tileT = Ws;                       // 64 x 66 shorts
        const int b = m0 >> 12, p0l = m0 & 4095;
        for (int g = 0; g < 4; ++g) {
            __syncthreads();
            #pragma unroll
            for (int j = 0; j < 4; ++j) {
                #pragma unroll
                for (int r = 0; r < 4; ++r)
                    tileT[(j * 16 + ln) * 66 + (w * 16 + quad * 4 + r)] =
                        f2bf(acc[g * 4 + j][r]);
            }
            __syncthreads();
            for (int e = tid; e < 2048; e += 256) {
                int ch = e >> 5, pp = (e & 31) * 2;
                unsigned lo = (unsigned short)tileT[ch * 66 + pp];
                unsigned hi = (unsigned short)tileT[ch * 66 + pp + 1];
                *(unsigned*)&outb[((size_t)b * CC + g * 64 + ch) * NN + p0l + pp] =
                    lo | (hi << 16);
            }
        }
    } else if (MODE == 6) {
        float trs = tanhf(auxf[0]);
        float* tileF = (float*)Ws;               // 64 x 66 floats
        const int b = m0 >> 12, p0l = m0 & 4095;
        for (int g = 0; g < 4; ++g) {
            __syncthreads();
            #pragma unroll
            for (int j = 0; j < 4; ++j) {
                int nt = g * 4 + j;
                int col = nt * 16 + ln;
                float wgl = bf2f(W16[(size_t)col * 257 + 256]);
                #pragma unroll
                for (int r = 0; r < 4; ++r) {
                    int row = rowb + r;
                    float mrow = mask[row];
                    float logit = acc[nt][r] + mrow * wgl;
                    float gate = mrow / (1.0f + __expf(-logit));
                    float corr = bf2f(auxb[(size_t)row * 256 + col]);
                    tileF[(j * 16 + ln) * 66 + (w * 16 + quad * 4 + r)] =
                        trs * gate * corr;
                }
            }
            __syncthreads();
            for (int e = tid; e < 4096; e += 256) {
                int ch = e >> 6, pos = e & 63;
                size_t o = ((size_t)b * CC + g * 64 + ch) * NN + p0l + pos;
                outf[o] = xres[o] + tileF[ch * 66 + pos];
            }
        }
    }
}

// ---------------------------------------------------------------------------
// Kernel 3: row-wise L2 normalize Q and K -> bf16
// ---------------------------------------------------------------------------
__global__ void qknorm_kernel(const float* __restrict__ Q, const float* __restrict__ K,
                              short* __restrict__ Q16, short* __restrict__ K16) {
    const int tid = threadIdx.x;
    const int wrow = blockIdx.x * 4 + (tid >> 6);
    const int lane = tid & 63;
    const float* base = (wrow < NTOT) ? (Q + (size_t)wrow * EE)
                                      : (K + (size_t)(wrow - NTOT) * EE);
    short* obase = (wrow < NTOT) ? (Q16 + (size_t)wrow * EE)
                                 : (K16 + (size_t)(wrow - NTOT) * EE);
    float v0 = base[lane];
    float v1 = (lane < 32) ? base[64 + lane] : 0.0f;
    float ss = v0 * v0 + v1 * v1;
    #pragma unroll
    for (int off = 32; off; off >>= 1) ss += __shfl_xor(ss, off, 64);
    float sc = 1.0f / fmaxf(sqrtf(ss), 1e-12f);
    obase[lane] = f2bf(v0 * sc);
    if (lane < 32) obase[64 + lane] = f2bf(v1 * sc);
}

// ---------------------------------------------------------------------------
// Kernel 4: barrier-free MFMA attention. 256 thr = 4 independent waves.
// Wave w: 32 queries (2 m-subtiles) x keys [w*1024, w*1024+1024).
// K/V fragments load directly from global (L2-resident); fixed-max softmax
// makes the key-split associative; end-of-block serial reduction in LDS.
// ---------------------------------------------------------------------------
__global__ __launch_bounds__(256, 2) void attn2_kernel(
    const short* __restrict__ Q16, const short* __restrict__ K16,
    const short* __restrict__ V16t, const float* __restrict__ mask,
    short* __restrict__ Ob16)
{
    __shared__ char lds[33280];
    short* Ps  = (short*)lds;                 // per-wave 32x40 shorts (in-loop)
    float* Red = (float*)lds;                 // 8192 floats (epilogue, overlaps Ps)
    float* LRed = (float*)(lds + 32768);      // 4 x 32 floats

    const int tid = threadIdx.x;
    const int w = tid >> 6, lane = tid & 63, ln = lane & 15, quad = lane >> 4;
    const int bidx = blockIdx.x;
    const int b  = (bidx & 7) >> 1;                       // XCD-pinned batch
    const int qt = ((bidx >> 3) << 1) | (bidx & 1);       // 0..127
    const int q0 = qt * 32;
    const size_t bN = (size_t)b * NN;
    const float C1 = 1.02062072615966f;                   // 10/sqrt(96)

    bf16x8 qf[2][3];
    #pragma unroll
    for (int mt = 0; mt < 2; ++mt)
        #pragma unroll
        for (int e = 0; e < 3; ++e)
            qf[mt][e] = *(const bf16x8*)&Q16[(bN + q0 + mt * 16 + ln) * EE + e * 32 + quad * 8];

    f32x4 acc[2][16];
    #pragma unroll
    for (int mt = 0; mt < 2; ++mt)
        #pragma unroll
        for (int ct = 0; ct < 16; ++ct) acc[mt][ct] = (f32x4){0.f, 0.f, 0.f, 0.f};
    float lsum[2][4] = {{0.f,0.f,0.f,0.f},{0.f,0.f,0.f,0.f}};

    short* Pw = Ps + w * 1280;
    const int kbase = w * 1024;

    for (int it = 0; it < 32; ++it) {
        const int k0 = kbase + it * 32;
        float mk0 = mask[bN + k0 + ln];
        float mk1 = mask[bN + k0 + 16 + ln];
        f32x4 s00 = (f32x4){0.f,0.f,0.f,0.f}, s01 = s00, s10 = s00, s11 = s00;
        #pragma unroll
        for (int e = 0; e < 3; ++e) {
            bf16x8 kf0 = *(const bf16x8*)&K16[(bN + k0 + ln) * EE + e * 32 + quad * 8];
            bf16x8 kf1 = *(const bf16x8*)&K16[(bN + k0 + 16 + ln) * EE + e * 32 + quad * 8];
            s00 = __builtin_amdgcn_mfma_f32_16x16x32_bf16(qf[0][e], kf0, s00, 0, 0, 0);
            s01 = __builtin_amdgcn_mfma_f32_16x16x32_bf16(qf[0][e], kf1, s01, 0, 0, 0);
            s10 = __builtin_amdgcn_mfma_f32_16x16x32_bf16(qf[1][e], kf0, s10, 0, 0, 0);
            s11 = __builtin_amdgcn_mfma_f32_16x16x32_bf16(qf[1][e], kf1, s11, 0, 0, 0);
        }
        bool z0 = mk0 >= 0.5f, z1 = mk1 >= 0.5f;
        #pragma unroll
        for (int r = 0; r < 4; ++r) {
            float p00 = z0 ? 0.f : __expf(fmaf(s00[r], C1, -C1));
            float p01 = z1 ? 0.f : __expf(fmaf(s01[r], C1, -C1));
            float p10 = z0 ? 0.f : __expf(fmaf(s10[r], C1, -C1));
            float p11 = z1 ? 0.f : __expf(fmaf(s11[r], C1, -C1));
            lsum[0][r] += p00 + p01;
            lsum[1][r] += p10 + p11;
            Pw[(quad * 4 + r) * 40 + ln]            = f2bf(p00);
            Pw[(quad * 4 + r) * 40 + 16 + ln]       = f2bf(p01);
            Pw[(16 + quad * 4 + r) * 40 + ln]       = f2bf(p10);
            Pw[(16 + quad * 4 + r) * 40 + 16 + ln]  = f2bf(p11);
        }
        bf16x8 pf0 = *(const bf16x8*)&Pw[ln * 40 + quad * 8];
        bf16x8 pf1 = *(const bf16x8*)&Pw[(16 + ln) * 40 + quad * 8];
        #pragma unroll
        for (int ct = 0; ct < 16; ++ct) {
            bf16x8 vf = *(const bf16x8*)&V16t[((size_t)b * CC + ct * 16 + ln) * NN + k0 + quad * 8];
            acc[0][ct] = __builtin_amdgcn_mfma_f32_16x16x32_bf16(pf0, vf, acc[0][ct], 0, 0, 0);
            acc[1][ct] = __builtin_amdgcn_mfma_f32_16x16x32_bf16(pf1, vf, acc[1][ct], 0, 0, 0);
        }
    }

    // in-wave l reduction over the 16 key-lanes; publish per-wave l
    #pragma unroll
    for (int mt = 0; mt < 2; ++mt)
        #pragma unroll
        for (int r = 0; r < 4; ++r) {
            float l = lsum[mt][r];
            l += __shfl_xor(l, 1, 64); l += __shfl_xor(l, 2, 64);
            l += __shfl_xor(l, 4, 64); l += __shfl_xor(l, 8, 64);
            LRed[w * 32 + mt * 16 + quad * 4 + r] = l;
        }

    // serial cross-wave O reduction through one 32KB buffer
    __syncthreads();                       // Ps dead from here; Red valid
    if (w == 3) {
        #pragma unroll
        for (int mt = 0; mt < 2; ++mt)
            #pragma unroll
            for (int ct = 0; ct < 16; ++ct)
                *(f32x4*)&Red[((mt * 16 + ct) * 64 + lane) * 4] = acc[mt][ct];
    }
    __syncthreads();
    if (w == 2) {
        #pragma unroll
        for (int mt = 0; mt < 2; ++mt)
            #pragma unroll
            for (int ct = 0; ct < 16; ++ct) {
                acc[mt][ct] += *(f32x4*)&Red[((mt * 16 + ct) * 64 + lane) * 4];
                *(f32x4*)&Red[((mt * 16 + ct) * 64 + lane) * 4] = acc[mt][ct];
            }
    }
    __syncthreads();
    if (w == 1) {
        #pragma unroll
        for (int mt = 0; mt < 2; ++mt)
            #pragma unroll
            for (int ct = 0; ct < 16; ++ct) {
                acc[mt][ct] += *(f32x4*)&Red[((mt * 16 + ct) * 64 + lane) * 4];
                *(f32x4*)&Red[((mt * 16 + ct) * 64 + lane) * 4] = acc[mt][ct];
            }
    }
    __syncthreads();
    if (w == 0) {
        float linv[2][4];
        #pragma unroll
        for (int mt = 0; mt < 2; ++mt)
            #pragma unroll
            for (int r = 0; r < 4; ++r) {
                int qi = mt * 16 + quad * 4 + r;
                linv[mt][r] = 1.0f / (LRed[qi] + LRed[32 + qi] + LRed[64 + qi] + LRed[96 + qi]);
            }
        #pragma unroll
        for (int mt = 0; mt < 2; ++mt)
            #pragma unroll
            for (int ct = 0; ct < 16; ++ct) {
                acc[mt][ct] += *(f32x4*)&Red[((mt * 16 + ct) * 64 + lane) * 4];
                #pragma unroll
                for (int r = 0; r < 4; ++r)
                    Ob16[(bN + q0 + mt * 16 + quad * 4 + r) * (size_t)CC + ct * 16 + ln] =
                        f2bf(acc[mt][ct][r] * linv[mt][r]);
            }
    }
}

// ---------------------------------------------------------------------------
extern "C" void kernel_launch(void* const* d_in, const int* in_sizes, int n_in,
                              void* d_out, int out_size, void* d_ws, size_t ws_size,
                              hipStream_t stream) {
    const float* x     = (const float*)d_in[0];
    const float* mask  = (const float*)d_in[1];
    const float* gamma = (const float*)d_in[2];
    const float* beta  = (const float*)d_in[3];
    const float* wq    = (const float*)d_in[4];
    const float* wk    = (const float*)d_in[5];
    const float* wv    = (const float*)d_in[6];
    const float* w_out = (const float*)d_in[7];
    const float* w_qm  = (const float*)d_in[8];
    const float* wd1   = (const float*)d_in[9];
    const float* wd2   = (const float*)d_in[10];
    const float* wg    = (const float*)d_in[11];
    const float* rs    = (const float*)d_in[12];
    float* out = (float*)d_out;

    const size_t NC = (size_t)NTOT * CC;
    const size_t NE = (size_t)NTOT * EE;
    float* Qb    = (float*)d_ws;            // NE f32
    float* Kb    = Qb + NE;                 // NE f32
    short* Xn16  = (short*)(Kb + NE);       // NC
    short* Xt16  = Xn16 + NC;               // NC
    short* Xnm16 = Xt16 + NC;               // NC
    short* Q16   = Xnm16 + NC;              // NE
    short* K16   = Q16 + NE;                // NE
    short* V16t  = K16 + NE;                // NC
    short* Ob16  = V16t + NC;               // NC
    short* D1in  = Ob16 + NC;               // NC
    short* Hid16 = D1in + NC;               // NC
    short* Cor16 = Hid16 + NC;              // NC
    short* W16   = Cor16 + NC;              // W16_TOTAL shorts
    // total ~87 MB (< the 96.5 MB already proven available)

    wconv_kernel<<<(W16_TOTAL + 255) / 256, 256, 0, stream>>>(wq, wk, wv, w_out,
                                                              wd1, wd2, wg, W16);
    ln_kernel<<<256, 256, 0, stream>>>(x, gamma, beta, mask, Xt16, Xn16, Xnm16);
    mgemm<6, 8, 0><<<256, 256, 0, stream>>>(Xn16, nullptr, W16 + OFF_WQ, 256,
                                            mask, w_qm, nullptr, Qb, nullptr, nullptr);
    mgemm<6, 8, 1><<<256, 256, 0, stream>>>(Xn16, nullptr, W16 + OFF_WK, 256,
                                            mask, nullptr, nullptr, Kb, nullptr, nullptr);
    mgemm<16, 8, 2><<<256, 256, 0, stream>>>(Xt16, nullptr, W16 + OFF_WV, 256,
                                             mask, nullptr, nullptr, nullptr, V16t, nullptr);
    qknorm_kernel<<<8192, 256, 0, stream>>>(Qb, Kb, Q16, K16);
    attn2_kernel<<<512, 256, 0, stream>>>(Q16, K16, V16t, mask, Ob16);
    mgemm<16, 8, 3><<<256, 256, 0, stream>>>(Ob16, nullptr, W16 + OFF_WO, 256,
                                             mask, nullptr, Xt16, nullptr, D1in, nullptr);
    mgemm<16, 16, 4><<<256, 256, 0, stream>>>(D1in, Xnm16, W16 + OFF_WD1, 512,
                                              mask, nullptr, nullptr, nullptr, Hid16, nullptr);
    mgemm<16, 8, 5><<<256, 256, 0, stream>>>(Hid16, nullptr, W16 + OFF_WD2, 256,
                                             mask, nullptr, nullptr, nullptr, Cor16, nullptr);
    mgemm<16, 8, 6><<<256, 256, 0, stream>>>(Cor16, nullptr, W16 + OFF_WG, 257,
                                             mask, rs, Cor16, out, nullptr, x);
}